// Round 5
// baseline (106.018 us; speedup 1.0000x reference)
//
#include <hip/hip_runtime.h>
#include <math.h>

#define BATCHN 4096
#define DMODEL 1024
#define NT 64
#define RANK 8
#define K2 512   // NT*RANK

typedef __attribute__((ext_vector_type(8))) short bf16x8;
typedef __attribute__((ext_vector_type(4))) float f32x4;

__device__ __forceinline__ void async16(void* lds, const void* g) {
    __builtin_amdgcn_global_load_lds(
        (const __attribute__((address_space(1))) void*)g,
        (__attribute__((address_space(3))) void*)lds, 16, 0, 0);
}

__device__ __forceinline__ short f2bf(float f) {
    unsigned u = __builtin_bit_cast(unsigned, f);
    u += 0x7fffu + ((u >> 16) & 1u);   // round-to-nearest-even
    return (short)(u >> 16);
}

// ---- convert (elementwise, coalesced) + norms partial sums ----
__global__ __launch_bounds__(256) void convert_kernel(
    const float* __restrict__ x, const float* __restrict__ enc,
    const float* __restrict__ V, const float* __restrict__ U,
    unsigned short* __restrict__ xb, unsigned short* __restrict__ Wb,
    unsigned short* __restrict__ Ub,
    float* __restrict__ su_part, float* __restrict__ sv_part)
{
    const int b = blockIdx.x, t = threadIdx.x;
    const float* src;
    unsigned short* dst;
    float* psum = nullptr;
    if (b < 2048) {                       // x: 4096*1024
        const int e0 = b * 2048 + t * 8;
        src = x + e0; dst = xb + e0;
    } else if (b < 2336) {                // W: 576*1024 (enc rows 0..63, V rows 64..575)
        const int e0 = (b - 2048) * 2048 + t * 8;
        const int row = e0 >> 10, col = e0 & 1023;
        if (row < 64) {
            src = enc + (size_t)row * 1024 + col;
        } else {
            src = V + (size_t)(row - 64) * 1024 + col;
            const int vrow = (b - 2048) * 2 - 64;
            psum = sv_part + (vrow >> 3) * 4 + ((vrow & 7) >> 1);
        }
        dst = Wb + e0;
    } else {                              // U native: 524288
        const int bi = b - 2336;
        const int e0 = bi * 2048 + t * 8;
        src = U + e0; dst = Ub + e0;
        psum = su_part + (bi >> 2) * 4 + (bi & 3);
    }
    float4 v0 = *(const float4*)src;
    float4 v1 = *(const float4*)(src + 4);
    bf16x8 o;
    o[0] = f2bf(v0.x); o[1] = f2bf(v0.y); o[2] = f2bf(v0.z); o[3] = f2bf(v0.w);
    o[4] = f2bf(v1.x); o[5] = f2bf(v1.y); o[6] = f2bf(v1.z); o[7] = f2bf(v1.w);
    *(bf16x8*)dst = o;

    if (psum) {
        float s = v0.x*v0.x + v0.y*v0.y + v0.z*v0.z + v0.w*v0.w
                + v1.x*v1.x + v1.y*v1.y + v1.z*v1.z + v1.w*v1.w;
        #pragma unroll
        for (int off = 32; off; off >>= 1) s += __shfl_down(s, off);
        __shared__ float red[4];
        if ((t & 63) == 0) red[t >> 6] = s;
        __syncthreads();
        if (t == 0) *psum = red[0] + red[1] + red[2] + red[3];
    }
}

// ---- K1: gate + raw-vx GEMM. C = xb @ Wb^T. grid (9,64), BM=64 BN=64 BK=128.
// 16 MFMAs per barrier per wave. bn==0: gate = relu(C-bias); bn>=1: vx = bf16(C).
__global__ __launch_bounds__(256) void gatevx_kernel(
    const unsigned short* __restrict__ A, const unsigned short* __restrict__ Bm,
    const float* __restrict__ bias,
    float* __restrict__ gate_out, unsigned short* __restrict__ vx_out)
{
    constexpr int BK = 128, KDIM = DMODEL;
    __shared__ unsigned short As[64 * BK];   // 16 KB
    __shared__ unsigned short Bs[64 * BK];   // 16 KB
    const int t = threadIdx.x;
    const int wave = t >> 6, lane = t & 63;
    const int bm = blockIdx.y, bn = blockIdx.x;
    const int wm = wave & 1, wn = wave >> 1;
    const int l15 = lane & 15, lq = lane >> 4;

    f32x4 acc[2][2] = {};
    const size_t Abase = (size_t)bm * 64 * KDIM;
    const size_t Bbase = (size_t)bn * 64 * KDIM;

    for (int k0 = 0; k0 < KDIM; k0 += BK) {
        // stage A+B: 4 rows x 16 chunks per call; LDS dest = uniform base + lane*16
        #pragma unroll
        for (int c = 0; c < 4; ++c) {
            const int r0 = wave * 16 + c * 4;
            const int row = r0 + (lane >> 4);
            const int g = l15 ^ (row & 15);            // global chunk (swizzled)
            async16(&As[r0 * BK], A + Abase + (size_t)row * KDIM + k0 + g * 8);
            async16(&Bs[r0 * BK], Bm + Bbase + (size_t)row * KDIM + k0 + g * 8);
        }
        __syncthreads();
        #pragma unroll
        for (int s = 0; s < 4; ++s) {
            const int kc = s * 4 + lq;
            const int cs = (kc ^ l15) * 8;             // de-swizzled chunk offset
            bf16x8 af[2], bfr[2];
            #pragma unroll
            for (int i = 0; i < 2; ++i) {
                const int m = wm * 32 + i * 16 + l15;  // m&15 == l15
                af[i] = *(const bf16x8*)&As[m * BK + cs];
            }
            #pragma unroll
            for (int j = 0; j < 2; ++j) {
                const int n = wn * 32 + j * 16 + l15;
                bfr[j] = *(const bf16x8*)&Bs[n * BK + cs];
            }
            #pragma unroll
            for (int i = 0; i < 2; ++i)
                #pragma unroll
                for (int j = 0; j < 2; ++j)
                    acc[i][j] = __builtin_amdgcn_mfma_f32_16x16x32_bf16(
                        af[i], bfr[j], acc[i][j], 0, 0, 0);
        }
        __syncthreads();
    }

    #pragma unroll
    for (int i = 0; i < 2; ++i) {
        const int rowb = bm * 64 + wm * 32 + i * 16 + lq * 4;
        #pragma unroll
        for (int j = 0; j < 2; ++j) {
            const int col = wn * 32 + j * 16 + l15;
            #pragma unroll
            for (int r = 0; r < 4; ++r) {
                const int row = rowb + r;
                const float v = acc[i][j][r];
                if (bn == 0) {
                    const float p = v - bias[col];
                    gate_out[(size_t)row * NT + col] = p > 0.f ? p : 0.f;
                } else {
                    vx_out[(size_t)row * K2 + (bn - 1) * 64 + col] = (unsigned short)f2bf(v);
                }
            }
        }
    }
}

// ---- K2: out = (gate ⊙ vx) @ U^T (U native [n][d][r] bf16). grid (8,64),
// BM=64 BN=128 BK=128, 4 k-iters, 32 MFMAs per barrier per wave.
// Block (0,0) finalizes fro.
__global__ __launch_bounds__(256) void out_kernel(
    const unsigned short* __restrict__ vx, const float* __restrict__ gate,
    const unsigned short* __restrict__ Ub, float* __restrict__ out,
    const float* __restrict__ su_part, const float* __restrict__ sv_part,
    float* __restrict__ fro)
{
    constexpr int BK = 128, KDIM = K2;
    __shared__ unsigned short As[64 * BK];        // 16 KB [m][chunk]
    __shared__ unsigned short Bs[16 * 128 * 8];   // 32 KB [kc(=n_local)][d][r]
    const int t = threadIdx.x;
    const int wave = t >> 6, lane = t & 63;
    const int bm = blockIdx.y, bn = blockIdx.x;
    const int wm = wave & 1, wn = wave >> 1;
    const int l15 = lane & 15, lq = lane >> 4;

    f32x4 acc[2][4] = {};

    for (int k0 = 0; k0 < KDIM; k0 += BK) {
        const int nb = k0 >> 3;                    // n base for this k-tile
        // A: manual gated staging; LDS write = uniform + lane*16 (conflict-free)
        #pragma unroll
        for (int i = 0; i < 4; ++i) {
            const int row = wave * 16 + i * 4 + (lane >> 4);
            const int grow = bm * 64 + row;
            const int p = l15;
            const int g = p ^ (row & 15);
            bf16x8 v = *(const bf16x8*)(vx + (size_t)grow * K2 + k0 + g * 8);
            const float gs = gate[(size_t)grow * NT + nb + g];
            bf16x8 o;
            #pragma unroll
            for (int e = 0; e < 8; ++e) {
                const float f = __builtin_bit_cast(float,
                    ((unsigned)(unsigned short)v[e]) << 16);
                o[e] = (short)(__builtin_bit_cast(unsigned, f * gs) >> 16);  // trunc
            }
            *(bf16x8*)&As[row * BK + p * 8] = o;
        }
        // B: async from native U; one call = one (kc, d-half), 64 lanes x 16B = 1 KB
        #pragma unroll
        for (int c = 0; c < 8; ++c) {
            const int kc = (c >> 1) * 4 + wave;
            const int dh = c & 1;
            async16(&Bs[kc * 1024 + dh * 512],
                    Ub + (size_t)(nb + kc) * (DMODEL * RANK)
                       + (size_t)(bn * 128 + dh * 64 + lane) * RANK);
        }
        __syncthreads();
        #pragma unroll
        for (int s = 0; s < 4; ++s) {
            const int kc = s * 4 + lq;
            const int cs = (kc ^ l15) * 8;
            bf16x8 af[2], bfr[4];
            #pragma unroll
            for (int i = 0; i < 2; ++i) {
                const int m = wm * 32 + i * 16 + l15;
                af[i] = *(const bf16x8*)&As[m * BK + cs];
            }
            #pragma unroll
            for (int j = 0; j < 4; ++j) {
                const int n = wn * 64 + j * 16 + l15;
                bfr[j] = *(const bf16x8*)&Bs[kc * 1024 + n * 8];
            }
            #pragma unroll
            for (int i = 0; i < 2; ++i)
                #pragma unroll
                for (int j = 0; j < 4; ++j)
                    acc[i][j] = __builtin_amdgcn_mfma_f32_16x16x32_bf16(
                        af[i], bfr[j], acc[i][j], 0, 0, 0);
        }
        __syncthreads();
    }

    #pragma unroll
    for (int i = 0; i < 2; ++i) {
        const int rowb = bm * 64 + wm * 32 + i * 16 + lq * 4;
        #pragma unroll
        for (int j = 0; j < 4; ++j) {
            const int col = bn * 128 + wn * 64 + j * 16 + l15;
            #pragma unroll
            for (int r = 0; r < 4; ++r)
                out[(size_t)(rowb + r) * DMODEL + col] = acc[i][j][r];
        }
    }

    if (bn == 0 && bm == 0 && t < NT) {
        float su = su_part[t * 4] + su_part[t * 4 + 1] + su_part[t * 4 + 2] + su_part[t * 4 + 3];
        float sv = sv_part[t * 4] + sv_part[t * 4 + 1] + sv_part[t * 4 + 2] + sv_part[t * 4 + 3];
        fro[t] = sqrtf(su) * sqrtf(sv) / sqrtf((float)(DMODEL * RANK));
    }
}

extern "C" void kernel_launch(void* const* d_in, const int* in_sizes, int n_in,
                              void* d_out, int out_size, void* d_ws, size_t ws_size,
                              hipStream_t stream) {
    const float* x    = (const float*)d_in[0];
    const float* V    = (const float*)d_in[1];
    const float* U    = (const float*)d_in[2];
    const float* enc  = (const float*)d_in[3];
    const float* bias = (const float*)d_in[4];

    float* out  = (float*)d_out;                       // [4096,1024]
    float* gate = out + (size_t)BATCHN * DMODEL;       // [4096,64] fp32
    float* fro  = gate + (size_t)BATCHN * NT;          // [64]

    char* ws = (char*)d_ws;
    unsigned short* xb = (unsigned short*)ws;                    // 8,388,608 B
    unsigned short* Wb = (unsigned short*)(ws + 8388608);        // 1,179,648 B
    unsigned short* Ub = (unsigned short*)(ws + 9568256);        // 1,048,576 B
    unsigned short* vx = (unsigned short*)(ws + 10616832);       // 4,194,304 B
    float* su_part     = (float*)(ws + 14811136);                // 1 KB
    float* sv_part     = (float*)(ws + 14812160);                // 1 KB

    convert_kernel<<<2592, 256, 0, stream>>>(x, enc, V, U, xb, Wb, Ub, su_part, sv_part);
    gatevx_kernel<<<dim3(9, 64), 256, 0, stream>>>(xb, Wb, bias, gate, vx);
    out_kernel<<<dim3(8, 64), 256, 0, stream>>>(vx, gate, Ub, out, su_part, sv_part, fro);
}